// Round 1
// baseline (308.909 us; speedup 1.0000x reference)
//
#include <hip/hip_runtime.h>
#include <math.h>

// Problem constants (fixed by reference: H=256, N=64, CH=1, L=2048)
#define NH   256
#define NN   64
#define LSEQ 2048
#define TT   64          // x-chunk length (i index)
#define JJ   (LSEQ/TT)   // 32 g-steps (j index)
#define SP   65          // padded LDS row stride (floats) -> bank = (row+col)%32
#define NTH  256

// k[h, 64j+i] = Re( (C^T dA^{64j}) . (dA^i dB) ) = Re( g_j . x_i )
// dA = 2*(I - dt/2 A)^-1 - I ;  dB = dt*(I - dt/2 A)^-1 B
__global__ __launch_bounds__(NTH) void ssm_kernel(
    const float* __restrict__ Ag,
    const float* __restrict__ Bg,
    const float* __restrict__ Cg,
    const float* __restrict__ LogDt,
    float* __restrict__ outp)
{
    __shared__ float Mr[NN*SP], Mi[NN*SP];   // A_back -> Minv -> dA -> even powers
    __shared__ float Qr[NN*SP], Qi[NN*SP];   // squaring ping-pong
    __shared__ float Xr[NN*SP], Xi[NN*SP];   // X[i][n] = x_i[n]
    __shared__ float gr[NN], gi[NN];
    __shared__ float br[NN], bi[NN];
    __shared__ float cr[NN], ci[NN];
    __shared__ float redr[4*NN], redi[4*NN]; // matvec/dot partials
    __shared__ float rgr[4*NN],  rgi[4*NN];  // g-step partials

    const int t    = threadIdx.x;
    const int lane = t & 63;
    const int wave = t >> 6;
    const int h    = blockIdx.x;

    const float dt   = expf(LogDt[h]);
    const float half = 0.5f * dt;

    // ---- load A_back = I - (dt/2) A  (padded SoA), plus B and C vectors ----
    const float2* A2 = (const float2*)(Ag + (size_t)h * NN * NN * 2);
    for (int idx = t; idx < NN*NN; idx += NTH) {
        int i = idx >> 6, j = idx & 63;
        float2 a = A2[idx];
        Mr[i*SP + j] = (i == j ? 1.0f : 0.0f) - half * a.x;
        Mi[i*SP + j] = -half * a.y;
    }
    if (t < NN) {
        float2 bv = ((const float2*)Bg)[h*NN + t];
        float2 cv = ((const float2*)Cg)[h*NN + t];
        br[t] = bv.x; bi[t] = bv.y;
        cr[t] = cv.x; ci[t] = cv.y;
    }
    __syncthreads();

    // ---- in-place Gauss-Jordan inversion (no pivoting; A_back is accretive) ----
    for (int k = 0; k < NN; ++k) {
        if (wave == 0) {  // scale row k; M[k][k] <- 1/pivot
            float pr = Mr[k*SP + k], pi = Mi[k*SP + k];
            float inv = 1.0f / (pr*pr + pi*pi);
            float ipr = pr*inv, ipi = -pi*inv;
            int j = lane;
            float vr, vi;
            if (j == k) { vr = ipr; vi = ipi; }
            else {
                float mr = Mr[k*SP + j], mi = Mi[k*SP + j];
                vr = mr*ipr - mi*ipi;
                vi = mr*ipi + mi*ipr;
            }
            Mr[k*SP + j] = vr; Mi[k*SP + j] = vi;
        }
        __syncthreads();
        {   // eliminate: wave w owns rows [16w, 16w+16)
            float ipr = Mr[k*SP + k], ipi = Mi[k*SP + k];
            int j = lane;
            float kr = Mr[k*SP + j], ki = Mi[k*SP + j];
            for (int r = 0; r < 16; ++r) {
                int i = wave*16 + r;
                if (i == k) continue;
                float fr = Mr[i*SP + k], fi = Mi[i*SP + k]; // broadcast
                float vr, vi;
                if (j == k) {
                    vr = -(fr*ipr - fi*ipi);
                    vi = -(fr*ipi + fi*ipr);
                } else {
                    vr = Mr[i*SP + j] - (fr*kr - fi*ki);
                    vi = Mi[i*SP + j] - (fr*ki + fi*kr);
                }
                Mr[i*SP + j] = vr; Mi[i*SP + j] = vi;
            }
        }
        __syncthreads();
    }

    // ---- dB = dt * Minv * B ----
    {
        float ar = 0.f, ai = 0.f;
        int n = lane;
        for (int q = 0; q < 16; ++q) {
            int kk = wave*16 + q;
            float mr = Mr[n*SP + kk], mi = Mi[n*SP + kk];
            float xr = br[kk], xi = bi[kk];
            ar += mr*xr - mi*xi;
            ai += mr*xi + mi*xr;
        }
        redr[wave*NN + n] = ar; redi[wave*NN + n] = ai;
    }
    __syncthreads();
    if (t < NN) {
        float sr = redr[t] + redr[NN+t] + redr[2*NN+t] + redr[3*NN+t];
        float si = redi[t] + redi[NN+t] + redi[2*NN+t] + redi[3*NN+t];
        br[t] = dt * sr; bi[t] = dt * si;
    }
    __syncthreads();

    // ---- dA = 2*Minv - I (in place) ----
    for (int idx = t; idx < NN*NN; idx += NTH) {
        int i = idx >> 6, j = idx & 63;
        Mr[i*SP + j] = 2.0f*Mr[i*SP + j] - (i == j ? 1.0f : 0.0f);
        Mi[i*SP + j] = 2.0f*Mi[i*SP + j];
    }
    __syncthreads();

    // ---- x_i = dA^i dB for i = 0..63 (sequential matvecs) ----
    if (t < NN) { Xr[t] = br[t]; Xi[t] = bi[t]; }
    __syncthreads();
    for (int i = 1; i < TT; ++i) {
        float ar = 0.f, ai = 0.f;
        int n = lane;
        for (int q = 0; q < 16; ++q) {
            int kk = wave*16 + q;
            float mr = Mr[n*SP + kk], mi = Mi[n*SP + kk];
            float xr = Xr[(i-1)*SP + kk], xi = Xi[(i-1)*SP + kk];
            ar += mr*xr - mi*xi;
            ai += mr*xi + mi*xr;
        }
        redr[wave*NN + n] = ar; redi[wave*NN + n] = ai;
        __syncthreads();
        if (t < NN) {
            Xr[i*SP + t] = redr[t] + redr[NN+t] + redr[2*NN+t] + redr[3*NN+t];
            Xi[i*SP + t] = redi[t] + redi[NN+t] + redi[2*NN+t] + redi[3*NN+t];
        }
        __syncthreads();
    }

    // ---- dA^64 via 6 squarings (ping-pong M <-> Q); 4x4 register tiles ----
    float *sR = Mr, *sI = Mi, *dR = Qr, *dI = Qi;
    for (int sq = 0; sq < 6; ++sq) {
        const int i0 = (t >> 4) * 4;   // wave-uniform-ish rows -> broadcast reads
        const int j0 = (t & 15) * 4;
        float accr[4][4], acci[4][4];
        #pragma unroll
        for (int a = 0; a < 4; ++a)
            #pragma unroll
            for (int b = 0; b < 4; ++b) { accr[a][b] = 0.f; acci[a][b] = 0.f; }
        for (int kk = 0; kk < NN; ++kk) {
            float brv[4], biv[4];
            #pragma unroll
            for (int b = 0; b < 4; ++b) {
                brv[b] = sR[kk*SP + j0 + b];
                biv[b] = sI[kk*SP + j0 + b];
            }
            #pragma unroll
            for (int a = 0; a < 4; ++a) {
                float arr = sR[(i0+a)*SP + kk], ari = sI[(i0+a)*SP + kk];
                #pragma unroll
                for (int b = 0; b < 4; ++b) {
                    accr[a][b] += arr*brv[b] - ari*biv[b];
                    acci[a][b] += arr*biv[b] + ari*brv[b];
                }
            }
        }
        #pragma unroll
        for (int a = 0; a < 4; ++a)
            #pragma unroll
            for (int b = 0; b < 4; ++b) {
                dR[(i0+a)*SP + j0 + b] = accr[a][b];
                dI[(i0+a)*SP + j0 + b] = acci[a][b];
            }
        __syncthreads();
        float* tp;
        tp = sR; sR = dR; dR = tp;
        tp = sI; sI = dI; dI = tp;
    }
    // dA^64 now in sR/sI

    // ---- outer phase: g_0 = C; per j: k[64j+i] = Re(g . x_i); g <- (dA^64)^T g ----
    if (t < NN) { gr[t] = cr[t]; gi[t] = ci[t]; }
    __syncthreads();
    for (int j = 0; j < JJ; ++j) {
        {   // dot partials: Re only
            int i = lane;
            float acc = 0.f;
            for (int q = 0; q < 16; ++q) {
                int nn = wave*16 + q;
                acc += gr[nn]*Xr[i*SP + nn] - gi[nn]*Xi[i*SP + nn];
            }
            redr[wave*NN + i] = acc;
        }
        {   // g-step partials: g'[n] = sum_k W[k][n] g[k]
            int n = lane;
            float ar = 0.f, ai = 0.f;
            for (int q = 0; q < 16; ++q) {
                int kk = wave*16 + q;
                float wr = sR[kk*SP + n], wi = sI[kk*SP + n];
                ar += wr*gr[kk] - wi*gi[kk];
                ai += wr*gi[kk] + wi*gr[kk];
            }
            rgr[wave*NN + n] = ar; rgi[wave*NN + n] = ai;
        }
        __syncthreads();
        if (t < NN) {
            outp[(size_t)h*LSEQ + j*TT + t] =
                redr[t] + redr[NN+t] + redr[2*NN+t] + redr[3*NN+t];
            gr[t] = rgr[t] + rgr[NN+t] + rgr[2*NN+t] + rgr[3*NN+t];
            gi[t] = rgi[t] + rgi[NN+t] + rgi[2*NN+t] + rgi[3*NN+t];
        }
        __syncthreads();
    }
}

extern "C" void kernel_launch(void* const* d_in, const int* in_sizes, int n_in,
                              void* d_out, int out_size, void* d_ws, size_t ws_size,
                              hipStream_t stream) {
    const float* A  = (const float*)d_in[0];
    const float* B  = (const float*)d_in[1];
    const float* C  = (const float*)d_in[2];
    const float* ld = (const float*)d_in[3];
    // d_in[4] is L (=2048), fixed at compile time
    float* out = (float*)d_out;
    ssm_kernel<<<dim3(NH), dim3(NTH), 0, stream>>>(A, B, C, ld, out);
}

// Round 3
// 245.309 us; speedup vs baseline: 1.2593x; 1.2593x over previous
//
#include <hip/hip_runtime.h>
#include <math.h>

// Problem constants (fixed by reference: H=256, N=64, CH=1, L=2048)
#define NH   256
#define NN   64
#define LSEQ 2048
#define SP   65      // padded LDS row stride: bank = (row+col)%32 for lane-varying reads
#define NTH  1024    // 16 waves/CU -> 4 waves/SIMD (occupancy 50%)

// k[h, 64j+i] = Re( g_j . x_i ),  g_j^T = C^T (dA^64)^j,  x_i = dA^i dB
// dA = 2*(I - dt/2 A)^-1 - I ;  dB = dt*(I - dt/2 A)^-1 B
__global__ __launch_bounds__(NTH, 4) void ssm_kernel(
    const float* __restrict__ Ag,
    const float* __restrict__ Bg,
    const float* __restrict__ Cg,
    const float* __restrict__ LogDt,
    float* __restrict__ outp)
{
    __shared__ float Mr[NN*SP], Mi[NN*SP];     // A_back -> Minv -> dA -> dA^2..dA^64
    __shared__ float Xtr[NN*SP], Xti[NN*SP];   // Xt[q][v] = x_v[q] at q*SP+v (transposed!)
    __shared__ float Gr[32*NN],  Gi[32*NN];    // g_j rows, stride 64
    __shared__ float br[NN], bi[NN];

    const int t    = threadIdx.x;
    const int lane = t & 63;
    const int h    = blockIdx.x;

    const float dt  = expf(LogDt[h]);
    const float hdt = 0.5f * dt;

    // ---- load A_back = I - (dt/2)A ; b ; c (c goes straight into G row 0) ----
    const float2* A2 = (const float2*)(Ag + (size_t)h * NN * NN * 2);
    for (int idx = t; idx < NN*NN; idx += NTH) {
        int i = idx >> 6, j = idx & 63;
        float2 a = A2[idx];
        Mr[i*SP + j] = (i == j ? 1.0f : 0.0f) - hdt * a.x;
        Mi[i*SP + j] = -hdt * a.y;
    }
    if (t < NN) {
        float2 bv = ((const float2*)Bg)[h*NN + t];
        float2 cv = ((const float2*)Cg)[h*NN + t];
        br[t] = bv.x; bi[t] = bv.y;
        Gr[t] = cv.x; Gi[t] = cv.y;
    }
    __syncthreads();

    // ---- in-place Gauss-Jordan INVERSION (A_back accretive => no pivoting) ----
    // wave w owns rows 4w..4w+3; thread column = lane. 2 barriers/step.
    // In-place inverse accumulation: after step k,
    //   row k:      M[k][j!=k] = M[k][j]/p,  M[k][k] = 1/p
    //   row i!=k:   M[i][j!=k] -= f*M[k][j]/p,  M[i][k] = -f/p   (f = old M[i][k])
    const int w = t >> 6;
    for (int k = 0; k < NN; ++k) {
        // phase A (reads only): pivot, scaled row-k value at own column, factors
        float pr = Mr[k*SP + k], pi = Mi[k*SP + k];
        float inv = 1.0f / (pr*pr + pi*pi);
        float ipr = pr*inv, ipi = -pi*inv;     // 1/p
        float skr, ski;                        // new row-k value at column `lane`
        if (lane == k) { skr = ipr; ski = ipi; }
        else {
            float krj = Mr[k*SP + lane], kij = Mi[k*SP + lane];
            skr = krj*ipr - kij*ipi;
            ski = krj*ipi + kij*ipr;
        }
        float fr[4], fi[4];
        #pragma unroll
        for (int r = 0; r < 4; ++r) {
            int i = 4*w + r;
            fr[r] = Mr[i*SP + k]; fi[r] = Mi[i*SP + k];   // broadcast reads
        }
        __syncthreads();
        // phase B (writes): scaled row k; eliminate own rows (col k -> -f/p)
        #pragma unroll
        for (int r = 0; r < 4; ++r) {
            int i = 4*w + r;
            if (i == k) {
                Mr[i*SP + lane] = skr;
                Mi[i*SP + lane] = ski;
            } else {
                float b_r = (lane == k) ? 0.0f : Mr[i*SP + lane];
                float b_i = (lane == k) ? 0.0f : Mi[i*SP + lane];
                Mr[i*SP + lane] = b_r - (fr[r]*skr - fi[r]*ski);
                Mi[i*SP + lane] = b_i - (fr[r]*ski + fi[r]*skr);
            }
        }
        __syncthreads();
    }

    // ---- dB = dt * Minv * b  -> Xt column 0  (16 threads per row, shfl reduce) ----
    {
        int n = t >> 4, part = t & 15;
        float ar = 0.f, ai = 0.f;
        #pragma unroll
        for (int qq = 0; qq < 4; ++qq) {
            int k = part*4 + qq;
            float mr = Mr[n*SP + k], mi = Mi[n*SP + k];
            float xr = br[k], xi = bi[k];
            ar += mr*xr - mi*xi;
            ai += mr*xi + mi*xr;
        }
        #pragma unroll
        for (int off = 8; off; off >>= 1) {
            ar += __shfl_xor(ar, off);
            ai += __shfl_xor(ai, off);
        }
        if (part == 0) { Xtr[n*SP + 0] = dt*ar; Xti[n*SP + 0] = dt*ai; }
    }
    __syncthreads();

    // ---- dA = 2*Minv - I (in place) ----
    for (int idx = t; idx < NN*NN; idx += NTH) {
        int i = idx >> 6, j = idx & 63;
        Mr[i*SP + j] = 2.0f*Mr[i*SP + j] - (i == j ? 1.0f : 0.0f);
        Mi[i*SP + j] = 2.0f*Mi[i*SP + j];
    }
    __syncthreads();

    // ---- x_1 = dA * x_0 ----
    {
        int n = t >> 4, part = t & 15;
        float ar = 0.f, ai = 0.f;
        #pragma unroll
        for (int qq = 0; qq < 4; ++qq) {
            int q = part*4 + qq;
            float mr = Mr[n*SP + q], mi = Mi[n*SP + q];
            float xr = Xtr[q*SP + 0], xi = Xti[q*SP + 0];
            ar += mr*xr - mi*xi;
            ai += mr*xi + mi*xr;
        }
        #pragma unroll
        for (int off = 8; off; off >>= 1) {
            ar += __shfl_xor(ar, off);
            ai += __shfl_xor(ai, off);
        }
        if (part == 0) { Xtr[n*SP + 1] = ar; Xti[n*SP + 1] = ai; }
    }
    __syncthreads();

    // ---- s = 1..6: M <- M^2 (register-tile, in place); then X-doubling for s<=5 ----
    // thread tile: rows {r0, r0+1}, cols {cc, cc+32}
    const int r0 = (t >> 5) * 2;
    const int cc = t & 31;
    for (int s = 1; s <= 6; ++s) {
        float a00r=0,a00i=0,a01r=0,a01i=0,a10r=0,a10i=0,a11r=0,a11i=0;
        for (int kk = 0; kk < NN; ++kk) {
            float b0r = Mr[kk*SP + cc],      b0i = Mi[kk*SP + cc];
            float b1r = Mr[kk*SP + cc + 32], b1i = Mi[kk*SP + cc + 32];
            float x0r = Mr[r0*SP + kk],      x0i = Mi[r0*SP + kk];
            float x1r = Mr[(r0+1)*SP + kk],  x1i = Mi[(r0+1)*SP + kk];
            a00r += x0r*b0r - x0i*b0i;  a00i += x0r*b0i + x0i*b0r;
            a01r += x0r*b1r - x0i*b1i;  a01i += x0r*b1i + x0i*b1r;
            a10r += x1r*b0r - x1i*b0i;  a10i += x1r*b0i + x1i*b0r;
            a11r += x1r*b1r - x1i*b1i;  a11i += x1r*b1i + x1i*b1r;
        }
        __syncthreads();   // all reads of M done
        Mr[r0*SP + cc]        = a00r;  Mi[r0*SP + cc]        = a00i;
        Mr[r0*SP + cc + 32]   = a01r;  Mi[r0*SP + cc + 32]   = a01i;
        Mr[(r0+1)*SP + cc]    = a10r;  Mi[(r0+1)*SP + cc]    = a10i;
        Mr[(r0+1)*SP + cc+32] = a11r;  Mi[(r0+1)*SP + cc+32] = a11i;
        __syncthreads();   // M = dA^(2^s)

        if (s <= 5) {
            // x_{C+r} = M * x_r for r in [0, C);  C = 2^s  (parallel doubling)
            const int Cc = 1 << s;
            const int R  = Cc * NN;     // number of output dots
            if (R >= NTH) {
                for (int d = t; d < R; d += NTH) {
                    int rv = d >> 6, n = d & 63;
                    float ar = 0.f, ai = 0.f;
                    for (int q = 0; q < NN; ++q) {
                        float mr = Mr[n*SP + q],  mi = Mi[n*SP + q];
                        float xr = Xtr[q*SP + rv], xi = Xti[q*SP + rv];
                        ar += mr*xr - mi*xi;
                        ai += mr*xi + mi*xr;
                    }
                    Xtr[n*SP + Cc + rv] = ar;
                    Xti[n*SP + Cc + rv] = ai;
                }
            } else {
                const int p = NTH / R;          // 8,4,2 for s=1,2,3
                int d = t / p, part = t % p;
                int rv = d >> 6, n = d & 63;
                int qper = NN / p;
                float ar = 0.f, ai = 0.f;
                for (int qq = 0; qq < qper; ++qq) {
                    int q = part*qper + qq;
                    float mr = Mr[n*SP + q],  mi = Mi[n*SP + q];
                    float xr = Xtr[q*SP + rv], xi = Xti[q*SP + rv];
                    ar += mr*xr - mi*xi;
                    ai += mr*xi + mi*xr;
                }
                for (int off = p >> 1; off; off >>= 1) {
                    ar += __shfl_xor(ar, off);
                    ai += __shfl_xor(ai, off);
                }
                if (part == 0) {
                    Xtr[n*SP + Cc + rv] = ar;
                    Xti[n*SP + Cc + rv] = ai;
                }
            }
            __syncthreads();
        }
    }
    // M = dA^64 = W ; Xt columns 0..63 = x_0..x_63

    // ---- g-chain: g_{j+1}[n] = sum_k W[k][n] g_j[k]  (31 sequential steps) ----
    {
        int n = t >> 4, part = t & 15;
        for (int j = 0; j < 31; ++j) {
            float ar = 0.f, ai = 0.f;
            #pragma unroll
            for (int qq = 0; qq < 4; ++qq) {
                int k = part*4 + qq;
                float wr = Mr[k*SP + n], wi = Mi[k*SP + n];
                float gr_ = Gr[j*NN + k], gi_ = Gi[j*NN + k];
                ar += wr*gr_ - wi*gi_;
                ai += wr*gi_ + wi*gr_;
            }
            #pragma unroll
            for (int off = 8; off; off >>= 1) {
                ar += __shfl_xor(ar, off);
                ai += __shfl_xor(ai, off);
            }
            if (part == 0) { Gr[(j+1)*NN + n] = ar; Gi[(j+1)*NN + n] = ai; }
            __syncthreads();
        }
    }

    // ---- output: k[h, j*64+i] = Re(g_j . x_i); thread handles j0 and j0+16 ----
    {
        int i  = lane;
        int j0 = t >> 6;   // wave id 0..15 (wave-uniform -> G reads broadcast)
        float acc0 = 0.f, acc1 = 0.f;
        for (int q = 0; q < NN; ++q) {
            float xr  = Xtr[q*SP + i], xi = Xti[q*SP + i];
            float g0r = Gr[j0*NN + q],      g0i = Gi[j0*NN + q];
            float g1r = Gr[(j0+16)*NN + q], g1i = Gi[(j0+16)*NN + q];
            acc0 += g0r*xr - g0i*xi;
            acc1 += g1r*xr - g1i*xi;
        }
        size_t base = (size_t)h * LSEQ;
        outp[base + j0*NN + i]      = acc0;
        outp[base + (j0+16)*NN + i] = acc1;
    }
}

extern "C" void kernel_launch(void* const* d_in, const int* in_sizes, int n_in,
                              void* d_out, int out_size, void* d_ws, size_t ws_size,
                              hipStream_t stream) {
    const float* A  = (const float*)d_in[0];
    const float* B  = (const float*)d_in[1];
    const float* C  = (const float*)d_in[2];
    const float* ld = (const float*)d_in[3];
    float* out = (float*)d_out;
    ssm_kernel<<<dim3(NH), dim3(NTH), 0, stream>>>(A, B, C, ld, out);
}

// Round 4
// 192.457 us; speedup vs baseline: 1.6051x; 1.2746x over previous
//
#include <hip/hip_runtime.h>
#include <math.h>

// Problem constants (fixed by reference: H=256, N=64, CH=1, L=2048)
#define NH   256
#define NN   64
#define LSEQ 2048
#define SP   65      // padded fp32 LDS row stride
#define BSTR 80      // bf16 row stride (elements): 160 B rows -> perfect bank spread for b128 frags
#define NTH  1024

typedef __attribute__((ext_vector_type(8))) short short8;     // 8 bf16 = 4 VGPRs (MFMA A/B frag)
typedef __attribute__((ext_vector_type(4))) float float4_t;   // MFMA C/D frag

static __device__ __forceinline__ unsigned short f2bf(float x) {   // RNE fp32->bf16
    unsigned u = __float_as_uint(x);
    u += 0x7fffu + ((u >> 16) & 1u);
    return (unsigned short)(u >> 16);
}
static __device__ __forceinline__ float bf2f(unsigned short h) {
    return __uint_as_float(((unsigned)h) << 16);
}
static __device__ __forceinline__ float lo2f(int p) { return __uint_as_float(((unsigned)p) << 16); }
static __device__ __forceinline__ float hi2f(int p) { return __uint_as_float((unsigned)p & 0xffff0000u); }
static __device__ __forceinline__ short8 neg8(short8 v) {          // flip bf16 sign bits
    union { short8 s; int i[4]; } u; u.s = v;
    u.i[0] ^= 0x80008000; u.i[1] ^= 0x80008000;
    u.i[2] ^= 0x80008000; u.i[3] ^= 0x80008000;
    return u.s;
}

// k[h, 64j+i] = Re( g_j . x_i ),  g_j^T = C^T (dA^64)^j,  x_i = dA^i dB
// dA = 2*(I - dt/2 A)^-1 - I ;  dB = dt*(I - dt/2 A)^-1 B
// Squarings dA^2..dA^64 run on MFMA with bf16 hi/lo split (error ~2^-16/product).
__global__ __launch_bounds__(NTH, 4) void ssm_kernel(
    const float* __restrict__ Ag,
    const float* __restrict__ Bg,
    const float* __restrict__ Cg,
    const float* __restrict__ LogDt,
    float* __restrict__ outp)
{
    // Union region: fp32 M (GJ phase) time-multiplexed with 8 bf16 arrays (squaring phase)
    __shared__ __align__(16) unsigned char uni[8 * NN * BSTR * 2];   // 81920 B
    __shared__ float Xtr[NN*SP], Xti[NN*SP];   // Xt[q][v] = x_v[q] at q*SP+v
    __shared__ float Gr[32*NN],  Gi[32*NN];    // g_j rows, stride 64
    __shared__ float br[NN], bi[NN];

    float* Mr = (float*)uni;                       // 64*65*4 = 16640 B
    float* Mi = (float*)(uni + NN*SP*4);           // ends at 33280 B
    unsigned short* RMrh = (unsigned short*)(uni +     0);   // row-major M.re hi
    unsigned short* RMrl = (unsigned short*)(uni + 10240);   // row-major M.re lo
    unsigned short* RMih = (unsigned short*)(uni + 20480);   // row-major M.im hi
    unsigned short* RMil = (unsigned short*)(uni + 30720);   // row-major M.im lo
    unsigned short* CMrh = (unsigned short*)(uni + 40960);   // col-major (M[r][c] at c*BSTR+r)
    unsigned short* CMrl = (unsigned short*)(uni + 51200);
    unsigned short* CMih = (unsigned short*)(uni + 61440);
    unsigned short* CMil = (unsigned short*)(uni + 71680);

    const int t    = threadIdx.x;
    const int lane = t & 63;
    const int h    = blockIdx.x;

    const float dt  = expf(LogDt[h]);
    const float hdt = 0.5f * dt;

    // ---- load A_back = I - (dt/2)A ; b ; c (c -> G row 0) ----
    const float2* A2 = (const float2*)(Ag + (size_t)h * NN * NN * 2);
    for (int idx = t; idx < NN*NN; idx += NTH) {
        int i = idx >> 6, j = idx & 63;
        float2 a = A2[idx];
        Mr[i*SP + j] = (i == j ? 1.0f : 0.0f) - hdt * a.x;
        Mi[i*SP + j] = -hdt * a.y;
    }
    if (t < NN) {
        float2 bv = ((const float2*)Bg)[h*NN + t];
        float2 cv = ((const float2*)Cg)[h*NN + t];
        br[t] = bv.x; bi[t] = bv.y;
        Gr[t] = cv.x; Gi[t] = cv.y;
    }
    __syncthreads();

    // ---- in-place Gauss-Jordan INVERSION (A_back accretive => no pivoting) ----
    const int w = t >> 6;
    for (int k = 0; k < NN; ++k) {
        float pr = Mr[k*SP + k], pi = Mi[k*SP + k];
        float inv = 1.0f / (pr*pr + pi*pi);
        float ipr = pr*inv, ipi = -pi*inv;     // 1/p
        float skr, ski;                        // new row-k value at column `lane`
        if (lane == k) { skr = ipr; ski = ipi; }
        else {
            float krj = Mr[k*SP + lane], kij = Mi[k*SP + lane];
            skr = krj*ipr - kij*ipi;
            ski = krj*ipi + kij*ipr;
        }
        float fr[4], fi[4];
        #pragma unroll
        for (int r = 0; r < 4; ++r) {
            int i = 4*w + r;
            fr[r] = Mr[i*SP + k]; fi[r] = Mi[i*SP + k];   // broadcast reads
        }
        __syncthreads();
        #pragma unroll
        for (int r = 0; r < 4; ++r) {
            int i = 4*w + r;
            if (i == k) {
                Mr[i*SP + lane] = skr;
                Mi[i*SP + lane] = ski;
            } else {
                float b_r = (lane == k) ? 0.0f : Mr[i*SP + lane];
                float b_i = (lane == k) ? 0.0f : Mi[i*SP + lane];
                Mr[i*SP + lane] = b_r - (fr[r]*skr - fi[r]*ski);
                Mi[i*SP + lane] = b_i - (fr[r]*ski + fi[r]*skr);
            }
        }
        __syncthreads();
    }

    // ---- dB = dt * Minv * b -> Xt column 0 ----
    {
        int n = t >> 4, part = t & 15;
        float ar = 0.f, ai = 0.f;
        #pragma unroll
        for (int qq = 0; qq < 4; ++qq) {
            int k = part*4 + qq;
            float mr = Mr[n*SP + k], mi = Mi[n*SP + k];
            ar += mr*br[k] - mi*bi[k];
            ai += mr*bi[k] + mi*br[k];
        }
        #pragma unroll
        for (int off = 8; off; off >>= 1) { ar += __shfl_xor(ar, off); ai += __shfl_xor(ai, off); }
        if (part == 0) { Xtr[n*SP + 0] = dt*ar; Xti[n*SP + 0] = dt*ai; }
    }
    __syncthreads();

    // ---- dA = 2*Minv - I (in place, fp32) ----
    for (int idx = t; idx < NN*NN; idx += NTH) {
        int i = idx >> 6, j = idx & 63;
        Mr[i*SP + j] = 2.0f*Mr[i*SP + j] - (i == j ? 1.0f : 0.0f);
        Mi[i*SP + j] = 2.0f*Mi[i*SP + j];
    }
    __syncthreads();

    // ---- x_1 = dA * x_0 (fp32 dA) ----
    {
        int n = t >> 4, part = t & 15;
        float ar = 0.f, ai = 0.f;
        #pragma unroll
        for (int qq = 0; qq < 4; ++qq) {
            int q = part*4 + qq;
            float mr = Mr[n*SP + q], mi = Mi[n*SP + q];
            float xr = Xtr[q*SP + 0], xi = Xti[q*SP + 0];
            ar += mr*xr - mi*xi;
            ai += mr*xi + mi*xr;
        }
        #pragma unroll
        for (int off = 8; off; off >>= 1) { ar += __shfl_xor(ar, off); ai += __shfl_xor(ai, off); }
        if (part == 0) { Xtr[n*SP + 1] = ar; Xti[n*SP + 1] = ai; }
    }
    __syncthreads();

    // ---- convert fp32 dA -> bf16 hi/lo, row-major + col-major (aliased region!) ----
    {
        float vr[4], vi[4];
        #pragma unroll
        for (int e = 0; e < 4; ++e) {
            int idx = t*4 + e;
            int i = idx >> 6, j = idx & 63;
            vr[e] = Mr[i*SP + j]; vi[e] = Mi[i*SP + j];
        }
        __syncthreads();   // all fp32 reads staged in regs before bf16 overwrites
        #pragma unroll
        for (int e = 0; e < 4; ++e) {
            int idx = t*4 + e;
            int i = idx >> 6, j = idx & 63;
            unsigned short rh = f2bf(vr[e]); unsigned short rl = f2bf(vr[e] - bf2f(rh));
            unsigned short ih = f2bf(vi[e]); unsigned short il = f2bf(vi[e] - bf2f(ih));
            RMrh[i*BSTR+j] = rh; RMrl[i*BSTR+j] = rl;
            RMih[i*BSTR+j] = ih; RMil[i*BSTR+j] = il;
            CMrh[j*BSTR+i] = rh; CMrl[j*BSTR+i] = rl;
            CMih[j*BSTR+i] = ih; CMil[j*BSTR+i] = il;
        }
        __syncthreads();
    }

    // ---- s = 1..6: M <- M^2 on MFMA (bf16x2 split); X-doubling after s<=5 ----
    // wave tile: 4x4 grid of 16x16 output tiles; mfma_f32_16x16x32_bf16
    //   A[m=lane&15][k=quad*8+j], B[k=quad*8+j][n=lane&15], D: col=lane&15,row=quad*4+reg
    const int wv = t >> 6;
    const int ti = wv >> 2, tj = wv & 3;
    const int fm = lane & 15;
    const int fq = lane >> 4;
    for (int s = 1; s <= 6; ++s) {
        float4_t accR = {0.f,0.f,0.f,0.f}, accI = {0.f,0.f,0.f,0.f};
        const int arow = ti*16 + fm;
        const int bcol = tj*16 + fm;
        #pragma unroll
        for (int ks = 0; ks < 2; ++ks) {
            const int kb = ks*32 + fq*8;
            short8 Arh = *(const short8*)(RMrh + arow*BSTR + kb);
            short8 Arl = *(const short8*)(RMrl + arow*BSTR + kb);
            short8 Aih = *(const short8*)(RMih + arow*BSTR + kb);
            short8 Ail = *(const short8*)(RMil + arow*BSTR + kb);
            short8 Brh = *(const short8*)(CMrh + bcol*BSTR + kb);
            short8 Brl = *(const short8*)(CMrl + bcol*BSTR + kb);
            short8 Bih = *(const short8*)(CMih + bcol*BSTR + kb);
            short8 Bil = *(const short8*)(CMil + bcol*BSTR + kb);
            short8 nAih = neg8(Aih), nAil = neg8(Ail);
            // Re: Ar*Br - Ai*Bi (3 split-terms each)
            accR = __builtin_amdgcn_mfma_f32_16x16x32_bf16(Arh, Brh, accR, 0,0,0);
            accR = __builtin_amdgcn_mfma_f32_16x16x32_bf16(Arh, Brl, accR, 0,0,0);
            accR = __builtin_amdgcn_mfma_f32_16x16x32_bf16(Arl, Brh, accR, 0,0,0);
            accR = __builtin_amdgcn_mfma_f32_16x16x32_bf16(nAih, Bih, accR, 0,0,0);
            accR = __builtin_amdgcn_mfma_f32_16x16x32_bf16(nAih, Bil, accR, 0,0,0);
            accR = __builtin_amdgcn_mfma_f32_16x16x32_bf16(nAil, Bih, accR, 0,0,0);
            // Im: Ar*Bi + Ai*Br
            accI = __builtin_amdgcn_mfma_f32_16x16x32_bf16(Arh, Bih, accI, 0,0,0);
            accI = __builtin_amdgcn_mfma_f32_16x16x32_bf16(Arh, Bil, accI, 0,0,0);
            accI = __builtin_amdgcn_mfma_f32_16x16x32_bf16(Arl, Bih, accI, 0,0,0);
            accI = __builtin_amdgcn_mfma_f32_16x16x32_bf16(Aih, Brh, accI, 0,0,0);
            accI = __builtin_amdgcn_mfma_f32_16x16x32_bf16(Aih, Brl, accI, 0,0,0);
            accI = __builtin_amdgcn_mfma_f32_16x16x32_bf16(Ail, Brh, accI, 0,0,0);
        }
        __syncthreads();   // all waves' frag reads done before in-place overwrite
        #pragma unroll
        for (int r = 0; r < 4; ++r) {
            int row = ti*16 + fq*4 + r;
            int col = tj*16 + fm;
            unsigned short vrh = f2bf(accR[r]);
            unsigned short vrl = f2bf(accR[r] - bf2f(vrh));
            unsigned short vih = f2bf(accI[r]);
            unsigned short vil = f2bf(accI[r] - bf2f(vih));
            RMrh[row*BSTR+col] = vrh; RMrl[row*BSTR+col] = vrl;
            RMih[row*BSTR+col] = vih; RMil[row*BSTR+col] = vil;
            CMrh[col*BSTR+row] = vrh; CMrl[col*BSTR+row] = vrl;
            CMih[col*BSTR+row] = vih; CMil[col*BSTR+row] = vil;
        }
        __syncthreads();   // M = dA^(2^s) in bf16 hi/lo

        if (s <= 5) {
            // x_{C+rv} = M * x_rv, rv in [0, C), C = 2^s; one full dot per thread
            // (row n wave-uniform-ish -> M reads broadcast; X reads spread over banks)
            const int Cc = 1 << s;
            const int R  = Cc * NN;
            for (int d = t; d < R; d += NTH) {
                int rv = d & (Cc - 1);
                int n  = d >> s;
                const int mb = n * BSTR;
                float ar = 0.f, ai = 0.f;
                #pragma unroll 8
                for (int qp = 0; qp < NN/2; ++qp) {
                    int prh = *(const int*)(RMrh + mb + 2*qp);
                    int prl = *(const int*)(RMrl + mb + 2*qp);
                    int pih = *(const int*)(RMih + mb + 2*qp);
                    int pil = *(const int*)(RMil + mb + 2*qp);
                    float m0r = lo2f(prh) + lo2f(prl);
                    float m1r = hi2f(prh) + hi2f(prl);
                    float m0i = lo2f(pih) + lo2f(pil);
                    float m1i = hi2f(pih) + hi2f(pil);
                    float x0r = Xtr[(2*qp  )*SP + rv], x0i = Xti[(2*qp  )*SP + rv];
                    float x1r = Xtr[(2*qp+1)*SP + rv], x1i = Xti[(2*qp+1)*SP + rv];
                    ar += m0r*x0r - m0i*x0i + m1r*x1r - m1i*x1i;
                    ai += m0r*x0i + m0i*x0r + m1r*x1i + m1i*x1r;
                }
                Xtr[n*SP + Cc + rv] = ar;
                Xti[n*SP + Cc + rv] = ai;
            }
            __syncthreads();
        }
    }
    // bf16 M = dA^64 = W ; Xt columns 0..63 = x_0..x_63

    // ---- g-chain: g_{j+1}[n] = sum_k W[k][n] g_j[k] (31 steps; col-major W reads) ----
    {
        int n = t >> 4, part = t & 15;
        const int cb = n * BSTR;
        for (int j = 0; j < 31; ++j) {
            float ar = 0.f, ai = 0.f;
            #pragma unroll
            for (int half = 0; half < 2; ++half) {
                int k0 = part*4 + half*2;
                int prh = *(const int*)(CMrh + cb + k0);
                int prl = *(const int*)(CMrl + cb + k0);
                int pih = *(const int*)(CMih + cb + k0);
                int pil = *(const int*)(CMil + cb + k0);
                float w0r = lo2f(prh) + lo2f(prl), w1r = hi2f(prh) + hi2f(prl);
                float w0i = lo2f(pih) + lo2f(pil), w1i = hi2f(pih) + hi2f(pil);
                float g0r = Gr[j*NN + k0],     g0i = Gi[j*NN + k0];
                float g1r = Gr[j*NN + k0 + 1], g1i = Gi[j*NN + k0 + 1];
                ar += w0r*g0r - w0i*g0i + w1r*g1r - w1i*g1i;
                ai += w0r*g0i + w0i*g0r + w1r*g1i + w1i*g1r;
            }
            #pragma unroll
            for (int off = 8; off; off >>= 1) { ar += __shfl_xor(ar, off); ai += __shfl_xor(ai, off); }
            if (part == 0) { Gr[(j+1)*NN + n] = ar; Gi[(j+1)*NN + n] = ai; }
            __syncthreads();
        }
    }

    // ---- output: k[h, j*64+i] = Re(g_j . x_i); thread handles j0 and j0+16 ----
    {
        int i  = lane;
        int j0 = t >> 6;
        float acc0 = 0.f, acc1 = 0.f;
        for (int q = 0; q < NN; ++q) {
            float xr  = Xtr[q*SP + i], xi = Xti[q*SP + i];
            float g0r = Gr[j0*NN + q],      g0i = Gi[j0*NN + q];
            float g1r = Gr[(j0+16)*NN + q], g1i = Gi[(j0+16)*NN + q];
            acc0 += g0r*xr - g0i*xi;
            acc1 += g1r*xr - g1i*xi;
        }
        size_t base = (size_t)h * LSEQ;
        outp[base + j0*NN + i]      = acc0;
        outp[base + (j0+16)*NN + i] = acc1;
    }
}

extern "C" void kernel_launch(void* const* d_in, const int* in_sizes, int n_in,
                              void* d_out, int out_size, void* d_ws, size_t ws_size,
                              hipStream_t stream) {
    const float* A  = (const float*)d_in[0];
    const float* B  = (const float*)d_in[1];
    const float* C  = (const float*)d_in[2];
    const float* ld = (const float*)d_in[3];
    float* out = (float*)d_out;
    ssm_kernel<<<dim3(NH), dim3(NTH), 0, stream>>>(A, B, C, ld, out);
}

// Round 5
// 127.874 us; speedup vs baseline: 2.4157x; 1.5051x over previous
//
#include <hip/hip_runtime.h>
#include <math.h>

// Problem constants (fixed by reference: H=256, N=64, CH=1, L=2048)
#define NH   256
#define NN   64
#define LSEQ 2048
#define SP   65      // fp32 row stride: 65 dwords === 1 mod 32 -> all patterns <=2-way banks
#define NTH  1024

typedef __attribute__((ext_vector_type(8))) short short8;     // 8 bf16 (MFMA A/B frag)
typedef __attribute__((ext_vector_type(4))) float float4_t;   // MFMA C/D frag

#define MFMA(a,b,c) __builtin_amdgcn_mfma_f32_16x16x32_bf16((a),(b),(c),0,0,0)

// Split 8 fp32 -> bf16 hi (truncated) + bf16 lo (remainder, truncated): 16-bit mantissa total.
// Pack via v_perm_b32: 3 VALU per value.
static __device__ __forceinline__ void split8(const float* x, short8& hi, short8& lo) {
    union { short8 s; unsigned u[4]; } H, L;
#pragma unroll
    for (int m = 0; m < 4; ++m) {
        unsigned e = __float_as_uint(x[2*m]);
        unsigned o = __float_as_uint(x[2*m+1]);
        H.u[m] = __builtin_amdgcn_perm(o, e, 0x07060302u);   // [hi16(o)|hi16(e)]
        float el = x[2*m]   - __uint_as_float(e & 0xffff0000u);
        float ol = x[2*m+1] - __uint_as_float(o & 0xffff0000u);
        L.u[m] = __builtin_amdgcn_perm(__float_as_uint(ol), __float_as_uint(el), 0x07060302u);
    }
    hi = H.s; lo = L.s;
}

static __device__ __forceinline__ short8 neg8(short8 v) {    // flip bf16 sign bits
    union { short8 s; int i[4]; } u; u.s = v;
#pragma unroll
    for (int m = 0; m < 4; ++m) u.i[m] ^= 0x80008000;
    return u.s;
}

// One 16x16 tile of complex P = A*B, K=64, bf16x2-split MFMA (lo*lo dropped).
// A fp32 row-major [row*SP+k] (consecutive reads); B fp32 row-major, read as
// columns [k*SP+col] (strided b32, conflict-free with SP=65).
template<bool IMAG>
static __device__ __forceinline__ void cmm_tile(
    const float* __restrict__ Ar, const float* __restrict__ Ai,
    const float* __restrict__ Br, const float* __restrict__ Bi,
    int arow, int bcol, int fq, float4_t& accR, float4_t& accI)
{
#pragma unroll
    for (int ks = 0; ks < 2; ++ks) {
        const int k0 = ks*32 + fq*8;
        float v[8];
        short8 Arh, Arl, Aih, Ail, Brh, Brl, Bih, Bil;
#pragma unroll
        for (int j = 0; j < 8; ++j) v[j] = Ar[arow*SP + k0 + j];
        split8(v, Arh, Arl);
#pragma unroll
        for (int j = 0; j < 8; ++j) v[j] = Ai[arow*SP + k0 + j];
        split8(v, Aih, Ail);
#pragma unroll
        for (int j = 0; j < 8; ++j) v[j] = Br[(k0 + j)*SP + bcol];
        split8(v, Brh, Brl);
#pragma unroll
        for (int j = 0; j < 8; ++j) v[j] = Bi[(k0 + j)*SP + bcol];
        split8(v, Bih, Bil);
        short8 nAih = neg8(Aih), nAil = neg8(Ail);
        // Re: Ar*Br - Ai*Bi (3 split terms each)
        accR = MFMA(Arh, Brh, accR); accR = MFMA(Arh, Brl, accR); accR = MFMA(Arl, Brh, accR);
        accR = MFMA(nAih, Bih, accR); accR = MFMA(nAih, Bil, accR); accR = MFMA(nAil, Bih, accR);
        if (IMAG) {
            accI = MFMA(Arh, Bih, accI); accI = MFMA(Arh, Bil, accI); accI = MFMA(Arl, Bih, accI);
            accI = MFMA(Aih, Brh, accI); accI = MFMA(Aih, Brl, accI); accI = MFMA(Ail, Brh, accI);
        }
    }
}

// k[h, 64j+i] = Re( g_j . x_i ),  g_j^T = C^T (dA^64)^j,  x_i = dA^i dB
// Minv = A_back^-1 via Newton (X1 = 2I - A_back; 2 steps -> residual ||E||^8 ~ 4e-9,
// valid since ||E|| = (dt/2)||A|| <~ 0.08). dA = 2*Minv - I; dB = dt*Minv*b.
__global__ __launch_bounds__(NTH, 4) void ssm_kernel(
    const float* __restrict__ Ag,
    const float* __restrict__ Bg,
    const float* __restrict__ Cg,
    const float* __restrict__ LogDt,
    float* __restrict__ outp)
{
    __shared__ float Abr[NN*SP], Abi[NN*SP];   // A_back (const through Newton)
    __shared__ float Xr_[NN*SP], Xi_[NN*SP];   // Newton iterate -> Minv -> dA^(2^s)
    __shared__ float Ttr[NN*SP], Tti[NN*SP];   // Newton temp T; then Xt[q*SP+v] = x_v[q]
    __shared__ float Gr_[32*SP], Gi_[32*SP];   // g_j rows, stride SP
    __shared__ float bvr[NN], bvi[NN];
    // total LDS = 3*33280 + 2*8320 + 512 = 117 KB -> 1 block/CU

    const int t    = threadIdx.x;
    const int lane = t & 63;
    const int wv   = t >> 6;            // wave 0..15
    const int ti   = wv >> 2, tj = wv & 3;
    const int fm   = lane & 15, fq = lane >> 4;
    const int h    = blockIdx.x;

    const float dt  = expf(LogDt[h]);
    const float hdt = 0.5f * dt;

    // ---- load A_back = I - (dt/2)A ; b ; c (c -> G row 0) ----
    const float2* A2 = (const float2*)(Ag + (size_t)h * NN * NN * 2);
    for (int idx = t; idx < NN*NN; idx += NTH) {
        int i = idx >> 6, j = idx & 63;
        float2 a = A2[idx];
        Abr[i*SP + j] = (i == j ? 1.0f : 0.0f) - hdt * a.x;
        Abi[i*SP + j] = -hdt * a.y;
    }
    if (t < NN) {
        float2 bv = ((const float2*)Bg)[h*NN + t];
        float2 cv = ((const float2*)Cg)[h*NN + t];
        bvr[t] = bv.x; bvi[t] = bv.y;
        Gr_[t] = cv.x; Gi_[t] = cv.y;
    }
    __syncthreads();

    // ---- Newton seed X1 = 2I - A_back ----
    for (int idx = t; idx < NN*NN; idx += NTH) {
        int i = idx >> 6, j = idx & 63;
        Xr_[i*SP + j] = (i == j ? 2.0f : 0.0f) - Abr[i*SP + j];
        Xi_[i*SP + j] = -Abi[i*SP + j];
    }
    __syncthreads();

    const int arow = ti*16 + fm;
    const int bcol = tj*16 + fm;

    // ---- 2 Newton steps: T = 2I - Ab*X ; X <- X*T ----
#pragma unroll 1
    for (int step = 0; step < 2; ++step) {
        float4_t aR = {0,0,0,0}, aI = {0,0,0,0};
        cmm_tile<true>(Abr, Abi, Xr_, Xi_, arow, bcol, fq, aR, aI);
        // T region dead here -> write without pre-barrier
#pragma unroll
        for (int r = 0; r < 4; ++r) {
            int row = ti*16 + fq*4 + r;
            Ttr[row*SP + bcol] = (row == bcol ? 2.0f : 0.0f) - aR[r];
            Tti[row*SP + bcol] = -aI[r];
        }
        __syncthreads();
        float4_t bR = {0,0,0,0}, bI = {0,0,0,0};
        cmm_tile<true>(Xr_, Xi_, Ttr, Tti, arow, bcol, fq, bR, bI);
        __syncthreads();   // all reads of X done before in-place overwrite
#pragma unroll
        for (int r = 0; r < 4; ++r) {
            int row = ti*16 + fq*4 + r;
            Xr_[row*SP + bcol] = bR[r];
            Xi_[row*SP + bcol] = bI[r];
        }
        __syncthreads();
    }
    // X = Minv

    // ---- dB = dt * Minv * b -> Xt col 0 (Xt aliases T) ----
    {
        int n = t >> 4, part = t & 15;
        float ar = 0.f, ai = 0.f;
#pragma unroll
        for (int qq = 0; qq < 4; ++qq) {
            int k = part*4 + qq;
            float mr = Xr_[n*SP + k], mi = Xi_[n*SP + k];
            ar += mr*bvr[k] - mi*bvi[k];
            ai += mr*bvi[k] + mi*bvr[k];
        }
#pragma unroll
        for (int off = 8; off; off >>= 1) { ar += __shfl_xor(ar, off); ai += __shfl_xor(ai, off); }
        if (part == 0) { Ttr[n*SP + 0] = dt*ar; Tti[n*SP + 0] = dt*ai; }
    }
    __syncthreads();

    // ---- dA = 2*Minv - I (in place) ----
    for (int idx = t; idx < NN*NN; idx += NTH) {
        int i = idx >> 6, j = idx & 63;
        Xr_[i*SP + j] = 2.0f*Xr_[i*SP + j] - (i == j ? 1.0f : 0.0f);
        Xi_[i*SP + j] = 2.0f*Xi_[i*SP + j];
    }
    __syncthreads();

    // ---- it = 1..7: [pre-work using X = dA^(2^(it-1))] + MFMA squaring ----
    // pre-work: it=1..4 scalar doubling d=it-1 (cols [C,2C)); it=5,6 MFMA doubling;
    // it=7: g1 = W^T c. After it: X = dA^(2^it). Final X = dA^128 for 2 g-chains.
#pragma unroll 1
    for (int it = 1; it <= 7; ++it) {
        if (it <= 4) {
            const int d = it - 1;
            const int C = 1 << d;
            const int R = C * NN;            // 64,128,256,512 dots
            const int p = NTH / R;           // 16,8,4,2 threads per dot
            const int qper = NN / p;
            int did = t / p, part = t % p;
            int rv = did & (C - 1);
            int n  = did >> d;
            float ar = 0.f, ai = 0.f;
            for (int qq = 0; qq < qper; ++qq) {
                int q = part*qper + qq;
                float mr = Xr_[n*SP + q], mi = Xi_[n*SP + q];
                float xr = Ttr[q*SP + rv], xi = Tti[q*SP + rv];
                ar += mr*xr - mi*xi;
                ai += mr*xi + mi*xr;
            }
            for (int off = p >> 1; off; off >>= 1) { ar += __shfl_xor(ar, off); ai += __shfl_xor(ai, off); }
            if (part == 0) { Ttr[n*SP + C + rv] = ar; Tti[n*SP + C + rv] = ai; }
        } else if (it == 5) {
            if (wv < 4) {   // out 64x16: cols 16..31
                float4_t aR = {0,0,0,0}, aI = {0,0,0,0};
                cmm_tile<true>(Xr_, Xi_, Ttr, Tti, wv*16 + fm, fm, fq, aR, aI);
#pragma unroll
                for (int r = 0; r < 4; ++r) {
                    int q = wv*16 + fq*4 + r;
                    Ttr[q*SP + 16 + fm] = aR[r];
                    Tti[q*SP + 16 + fm] = aI[r];
                }
            }
        } else if (it == 6) {
            if (wv < 8) {   // out 64x32: cols 32..63
                int t5 = wv >> 1, j5 = wv & 1;
                float4_t aR = {0,0,0,0}, aI = {0,0,0,0};
                cmm_tile<true>(Xr_, Xi_, Ttr, Tti, t5*16 + fm, j5*16 + fm, fq, aR, aI);
#pragma unroll
                for (int r = 0; r < 4; ++r) {
                    int q = t5*16 + fq*4 + r;
                    Ttr[q*SP + 32 + j5*16 + fm] = aR[r];
                    Tti[q*SP + 32 + j5*16 + fm] = aI[r];
                }
            }
        } else {   // it == 7: g1[n] = sum_k W[k][n] c[k], W = dA^64
            int n = t >> 4, part = t & 15;
            float ar = 0.f, ai = 0.f;
#pragma unroll
            for (int qq = 0; qq < 4; ++qq) {
                int k = part*4 + qq;
                float wr = Xr_[k*SP + n], wi = Xi_[k*SP + n];
                ar += wr*Gr_[k] - wi*Gi_[k];
                ai += wr*Gi_[k] + wi*Gr_[k];
            }
#pragma unroll
            for (int off = 8; off; off >>= 1) { ar += __shfl_xor(ar, off); ai += __shfl_xor(ai, off); }
            if (part == 0) { Gr_[SP + n] = ar; Gi_[SP + n] = ai; }
        }
        // squaring (all 16 waves)
        float4_t sR = {0,0,0,0}, sI = {0,0,0,0};
        cmm_tile<true>(Xr_, Xi_, Xr_, Xi_, arow, bcol, fq, sR, sI);
        __syncthreads();   // all reads (pre-work + frags) done
#pragma unroll
        for (int r = 0; r < 4; ++r) {
            int row = ti*16 + fq*4 + r;
            Xr_[row*SP + bcol] = sR[r];
            Xi_[row*SP + bcol] = sI[r];
        }
        __syncthreads();
    }
    // X = dA^128 ; Xt cols 0..63 = x_0..x_63 ; G rows 0,1 seeded

    // ---- two parallel g-chains: g_{j+2}[n] = sum_k W2[k][n] g_j[k] ----
    {
        int chain = t >> 9;          // 0: even j, 1: odd j
        int rem = t & 511;
        int n = rem >> 3;            // 0..63
        int part = rem & 7;          // 8 lanes per dot
#pragma unroll 1
        for (int m = 0; m < 15; ++m) {
            int j = 2*m + chain;
            float ar = 0.f, ai = 0.f;
#pragma unroll
            for (int qq = 0; qq < 8; ++qq) {
                int k = part*8 + qq;
                float wr = Xr_[k*SP + n], wi = Xi_[k*SP + n];
                float gr = Gr_[j*SP + k], gi = Gi_[j*SP + k];
                ar += wr*gr - wi*gi;
                ai += wr*gi + wi*gr;
            }
#pragma unroll
            for (int off = 4; off; off >>= 1) { ar += __shfl_xor(ar, off); ai += __shfl_xor(ai, off); }
            if (part == 0) { Gr_[(j+2)*SP + n] = ar; Gi_[(j+2)*SP + n] = ai; }
            __syncthreads();
        }
    }

    // ---- output K[j][i] = Re(g_j . x_i) via MFMA, direct global store ----
    if (wv < 8) {
        int to = wv >> 2, jo = wv & 3;   // 2x4 tiles covering 32x64
        float4_t aR = {0,0,0,0}, dummy = {0,0,0,0};
        cmm_tile<false>(Gr_, Gi_, Ttr, Tti, to*16 + fm, jo*16 + fm, fq, aR, dummy);
        size_t base = (size_t)h * LSEQ;
#pragma unroll
        for (int r = 0; r < 4; ++r) {
            int j = to*16 + fq*4 + r;
            int i = jo*16 + fm;
            outp[base + j*NN + i] = aR[r];
        }
    }
}

extern "C" void kernel_launch(void* const* d_in, const int* in_sizes, int n_in,
                              void* d_out, int out_size, void* d_ws, size_t ws_size,
                              hipStream_t stream) {
    const float* A  = (const float*)d_in[0];
    const float* B  = (const float*)d_in[1];
    const float* C  = (const float*)d_in[2];
    const float* ld = (const float*)d_in[3];
    float* out = (float*)d_out;
    ssm_kernel<<<dim3(NH), dim3(NTH), 0, stream>>>(A, B, C, ld, out);
}

// Round 6
// 117.566 us; speedup vs baseline: 2.6275x; 1.0877x over previous
//
#include <hip/hip_runtime.h>
#include <math.h>

// Problem constants (fixed by reference: H=256, N=64, CH=1, L=2048)
#define NH   256
#define NN   64
#define LSEQ 2048
#define SDW  68      // dword row stride: 68 mod 32 = 4 -> b128 16-lane phases tile 32 banks x2
#define NTH  1024

typedef __attribute__((ext_vector_type(8))) short short8;     // 8 bf16 (MFMA A/B frag)
typedef __attribute__((ext_vector_type(4))) float float4_t;   // MFMA C/D frag

#define MFMA(a,b,c) __builtin_amdgcn_mfma_f32_16x16x32_bf16((a),(b),(c),0,0,0)
#define PERM_HI 0x07060302u   // [a.hi16 | b.hi16]
#define PERM_LO 0x05040100u   // [a.lo16 | b.lo16]

// packed element: dword = [bf16hi | bf16lo], value = hi + lo (16-bit mantissa)
static __device__ __forceinline__ unsigned pack2(float v) {
    unsigned hv = __float_as_uint(v) & 0xffff0000u;
    float lo = v - __uint_as_float(hv);
    return __builtin_amdgcn_perm(hv, __float_as_uint(lo), PERM_HI);
}
static __device__ __forceinline__ float unpack2(unsigned w) {
    return __uint_as_float(w & 0xffff0000u) + __uint_as_float(w << 16);
}

// hi/lo frags from 8 fp32 bit-patterns in registers
static __device__ __forceinline__ void frag_vals(const unsigned* e, short8& hi, short8& lo) {
    unsigned lb[8];
#pragma unroll
    for (int m = 0; m < 8; ++m) {
        unsigned hv = e[m] & 0xffff0000u;
        lb[m] = __float_as_uint(__uint_as_float(e[m]) - __uint_as_float(hv));
    }
    union { short8 s; unsigned u[4]; } H, L;
#pragma unroll
    for (int m = 0; m < 4; ++m) {
        H.u[m] = __builtin_amdgcn_perm(e[2*m+1],  e[2*m],  PERM_HI);
        L.u[m] = __builtin_amdgcn_perm(lb[2*m+1], lb[2*m], PERM_HI);
    }
    hi = H.s; lo = L.s;
}
// frags from 8 consecutive fp32 in LDS (2x ds_read_b128 + split)
static __device__ __forceinline__ void frag_f32(const float* p, short8& hi, short8& lo) {
    const uint4* q = (const uint4*)p;
    uint4 d0 = q[0], d1 = q[1];
    unsigned e[8] = {d0.x, d0.y, d0.z, d0.w, d1.x, d1.y, d1.z, d1.w};
    frag_vals(e, hi, lo);
}
// frags from 8 consecutive packed dwords in LDS (2x ds_read_b128 + 8 perms, no float math)
static __device__ __forceinline__ void frag_packed(const unsigned* p, short8& hi, short8& lo) {
    const uint4* q = (const uint4*)p;
    uint4 d0 = q[0], d1 = q[1];
    unsigned e[8] = {d0.x, d0.y, d0.z, d0.w, d1.x, d1.y, d1.z, d1.w};
    union { short8 s; unsigned u[4]; } H, L;
#pragma unroll
    for (int m = 0; m < 4; ++m) {
        H.u[m] = __builtin_amdgcn_perm(e[2*m+1], e[2*m], PERM_HI);
        L.u[m] = __builtin_amdgcn_perm(e[2*m+1], e[2*m], PERM_LO);
    }
    hi = H.s; lo = L.s;
}
static __device__ __forceinline__ short8 neg8(short8 v) {
    union { short8 s; int i[4]; } u; u.s = v;
#pragma unroll
    for (int m = 0; m < 4; ++m) u.i[m] ^= 0x80008000;
    return u.s;
}

// One 16x16 tile of complex P = A*B, K=64. A read as rows [arow*SDW+k0..],
// B read as rows of the B-TRANSPOSE array [bcol*SDW+k0..] (both b128-clean).
template<bool AP, bool BP, bool IMAG>
static __device__ __forceinline__ void cmm_tile(
    const void* Ar_, const void* Ai_, const void* Br_, const void* Bi_,
    int arow, int bcol, int fq, float4_t& accR, float4_t& accI)
{
#pragma unroll
    for (int ks = 0; ks < 2; ++ks) {
        const int k0 = ks*32 + fq*8;
        short8 Arh, Arl, Aih, Ail, Brh, Brl, Bih, Bil;
        if (AP) {
            frag_packed((const unsigned*)Ar_ + arow*SDW + k0, Arh, Arl);
            frag_packed((const unsigned*)Ai_ + arow*SDW + k0, Aih, Ail);
        } else {
            frag_f32((const float*)Ar_ + arow*SDW + k0, Arh, Arl);
            frag_f32((const float*)Ai_ + arow*SDW + k0, Aih, Ail);
        }
        if (BP) {
            frag_packed((const unsigned*)Br_ + bcol*SDW + k0, Brh, Brl);
            frag_packed((const unsigned*)Bi_ + bcol*SDW + k0, Bih, Bil);
        } else {
            frag_f32((const float*)Br_ + bcol*SDW + k0, Brh, Brl);
            frag_f32((const float*)Bi_ + bcol*SDW + k0, Bih, Bil);
        }
        short8 nAih = neg8(Aih), nAil = neg8(Ail);
        accR = MFMA(Arh, Brh, accR); accR = MFMA(Arh, Brl, accR); accR = MFMA(Arl, Brh, accR);
        accR = MFMA(nAih, Bih, accR); accR = MFMA(nAih, Bil, accR); accR = MFMA(nAil, Bih, accR);
        if (IMAG) {
            accI = MFMA(Arh, Bih, accI); accI = MFMA(Arh, Bil, accI); accI = MFMA(Arl, Bih, accI);
            accI = MFMA(Aih, Brh, accI); accI = MFMA(Aih, Brl, accI); accI = MFMA(Ail, Brh, accI);
        }
    }
}

// k[h, 64j+i] = Re( g_j . x_i ),  g_j^T = C^T (dA^64)^j,  x_i = dA^i dB
// Minv via Newton from X1 = I + (dt/2)A (residual ||E||^8, E = (dt/2)A, ||E|| <~ 0.13)
__global__ __launch_bounds__(NTH, 4) void ssm_kernel(
    const float* __restrict__ Ag,
    const float* __restrict__ Bg,
    const float* __restrict__ Cg,
    const float* __restrict__ LogDt,
    float* __restrict__ outp)
{
    // carve one aligned LDS block (all offsets multiples of 16)
    __shared__ __align__(16) unsigned char lds[130688];
    unsigned* XRr = (unsigned*)(lds +      0);   // packed X row-major (re)
    unsigned* XRi = (unsigned*)(lds +  17408);   // packed X row-major (im)
    unsigned* XTr = (unsigned*)(lds +  34816);   // packed X^T (re)  [B-operand view]
    unsigned* XTi = (unsigned*)(lds +  52224);   // packed X^T (im)
    unsigned* U0u = (unsigned*)(lds +  69632);   // Newton T^T packed  /  Xt fp32 (re)
    unsigned* U1u = (unsigned*)(lds +  87040);   //                    /  Xt fp32 (im)
    float*    U0f = (float*)U0u;                 // Xt[v*SDW+q] = x_v[q]
    float*    U1f = (float*)U1u;
    float*    Grf = (float*)(lds + 104448);      // g_j rows, stride SDW (32 rows)
    float*    Gif = (float*)(lds + 113152);
    float*    Kof = (float*)(lds + 121856);      // output stage 32 x 65
    float*    bvr = (float*)(lds + 130176);
    float*    bvi = (float*)(lds + 130432);

    const int t    = threadIdx.x;
    const int lane = t & 63;
    const int wv   = t >> 6;                 // 0..15
    const int ti   = wv >> 2, tj = wv & 3;
    const int fm   = lane & 15, fq = lane >> 4;
    const int h    = blockIdx.x;

    const float dt  = expf(LogDt[h]);
    const float hdt = 0.5f * dt;

    const float2* A2 = (const float2*)(Ag + (size_t)h * NN * NN * 2);

    // ---- seed X1 = I + (dt/2)A (packed, both orientations); load b, c ----
#pragma unroll
    for (int e = 0; e < 4; ++e) {
        int idx = t + e*NTH;
        int i = idx >> 6, j = idx & 63;
        float2 a = A2[idx];
        unsigned pr = pack2((i == j ? 1.0f : 0.0f) + hdt * a.x);
        unsigned pi = pack2(hdt * a.y);
        XRr[i*SDW + j] = pr; XRi[i*SDW + j] = pi;
        XTr[j*SDW + i] = pr; XTi[j*SDW + i] = pi;
    }
    if (t < NN) {
        float2 bv = ((const float2*)Bg)[h*NN + t];
        float2 cv = ((const float2*)Cg)[h*NN + t];
        bvr[t] = bv.x; bvi[t] = bv.y;
        Grf[t] = cv.x; Gif[t] = cv.y;   // g_0 = c
    }
    __syncthreads();

    const int arow = ti*16 + fm;
    const int bcol = tj*16 + fm;

    // ---- 2 Newton steps: T = 2I - Ab*X (Ab from global); X <- X*T ----
#pragma unroll 1
    for (int step = 0; step < 2; ++step) {
        float4_t aR = {0,0,0,0}, aI = {0,0,0,0};
#pragma unroll
        for (int ks = 0; ks < 2; ++ks) {
            const int k0 = ks*32 + fq*8;
            unsigned vr[8], vi[8];
#pragma unroll
            for (int j = 0; j < 8; ++j) {
                float2 a = A2[arow*NN + k0 + j];
                vr[j] = __float_as_uint((arow == k0 + j ? 1.0f : 0.0f) - hdt * a.x);
                vi[j] = __float_as_uint(-hdt * a.y);
            }
            short8 Arh, Arl, Aih, Ail, Brh, Brl, Bih, Bil;
            frag_vals(vr, Arh, Arl);
            frag_vals(vi, Aih, Ail);
            frag_packed(XTr + bcol*SDW + k0, Brh, Brl);
            frag_packed(XTi + bcol*SDW + k0, Bih, Bil);
            short8 nAih = neg8(Aih), nAil = neg8(Ail);
            aR = MFMA(Arh, Brh, aR); aR = MFMA(Arh, Brl, aR); aR = MFMA(Arl, Brh, aR);
            aR = MFMA(nAih, Bih, aR); aR = MFMA(nAih, Bil, aR); aR = MFMA(nAil, Bih, aR);
            aI = MFMA(Arh, Bih, aI); aI = MFMA(Arh, Bil, aI); aI = MFMA(Arl, Bih, aI);
            aI = MFMA(Aih, Brh, aI); aI = MFMA(Aih, Brl, aI); aI = MFMA(Ail, Brh, aI);
        }
        // write T^T packed into U (dead region)
#pragma unroll
        for (int r = 0; r < 4; ++r) {
            int row = ti*16 + fq*4 + r;
            U0u[bcol*SDW + row] = pack2((row == bcol ? 2.0f : 0.0f) - aR[r]);
            U1u[bcol*SDW + row] = pack2(-aI[r]);
        }
        __syncthreads();
        float4_t bR = {0,0,0,0}, bI = {0,0,0,0};
        cmm_tile<true, true, true>(XRr, XRi, U0u, U1u, arow, bcol, fq, bR, bI);
        __syncthreads();   // all reads of X done before overwrite
#pragma unroll
        for (int r = 0; r < 4; ++r) {
            int row = ti*16 + fq*4 + r;
            unsigned pr = pack2(bR[r]), pi = pack2(bI[r]);
            XRr[row*SDW + bcol] = pr; XRi[row*SDW + bcol] = pi;
            XTr[bcol*SDW + row] = pr; XTi[bcol*SDW + row] = pi;
        }
        __syncthreads();
    }
    // X = Minv

    // ---- dB = dt * Minv * b -> Xt row 0 (U now fp32 Xt) ----
    {
        int n = t >> 4, part = t & 15;
        float ar = 0.f, ai = 0.f;
#pragma unroll
        for (int qq = 0; qq < 4; ++qq) {
            int k = part + 16*qq;
            float mr = unpack2(XRr[n*SDW + k]), mi = unpack2(XRi[n*SDW + k]);
            ar += mr*bvr[k] - mi*bvi[k];
            ai += mr*bvi[k] + mi*bvr[k];
        }
#pragma unroll
        for (int off = 8; off; off >>= 1) { ar += __shfl_xor(ar, off); ai += __shfl_xor(ai, off); }
        if (part == 0) { U0f[n] = dt*ar; U1f[n] = dt*ai; }
    }
    __syncthreads();

    // ---- dA = 2*Minv - I (in place, packed, both orientations) ----
#pragma unroll
    for (int e = 0; e < 4; ++e) {
        int idx = t + e*NTH;
        int i = idx >> 6, j = idx & 63;
        float vr = 2.0f*unpack2(XRr[i*SDW + j]) - (i == j ? 1.0f : 0.0f);
        float vi = 2.0f*unpack2(XRi[i*SDW + j]);
        unsigned pr = pack2(vr), pi = pack2(vi);
        XRr[i*SDW + j] = pr; XRi[i*SDW + j] = pi;
        XTr[j*SDW + i] = pr; XTi[j*SDW + i] = pi;
    }
    __syncthreads();

    // ---- it = 1..7: pre-work (uses X = dA^(2^(it-1))) + squaring ----
#pragma unroll 1
    for (int it = 1; it <= 7; ++it) {
        if (it <= 4) {
            // scalar doubling: x_{C+rv} = X * x_rv, rv in [0,C)
            const int d = it - 1;
            const int C = 1 << d;
            const int lgp = 4 - d;          // p = 16,8,4,2 threads per dot
            const int p = 1 << lgp;
            const int qper = NN >> lgp;
            int did = t >> lgp, part = t & (p - 1);
            int rv = did & (C - 1);
            int n  = did >> d;
            float ar = 0.f, ai = 0.f;
            for (int qq = 0; qq < qper; ++qq) {
                int q = part + p*qq;
                float mr = unpack2(XRr[n*SDW + q]), mi = unpack2(XRi[n*SDW + q]);
                float xr = U0f[rv*SDW + q], xi = U1f[rv*SDW + q];
                ar += mr*xr - mi*xi;
                ai += mr*xi + mi*xr;
            }
            for (int off = p >> 1; off; off >>= 1) { ar += __shfl_xor(ar, off); ai += __shfl_xor(ai, off); }
            if (part == 0) { U0f[(C + rv)*SDW + n] = ar; U1f[(C + rv)*SDW + n] = ai; }
        } else if (it == 5) {
            if (wv < 4) {   // x_{16..31} = dA^16 * x_{0..15}
                float4_t aR = {0,0,0,0}, aI = {0,0,0,0};
                cmm_tile<true, false, true>(XRr, XRi, U0f, U1f, wv*16 + fm, fm, fq, aR, aI);
#pragma unroll
                for (int r = 0; r < 4; ++r) {
                    int q = wv*16 + fq*4 + r;
                    U0f[(16 + fm)*SDW + q] = aR[r];
                    U1f[(16 + fm)*SDW + q] = aI[r];
                }
            }
        } else if (it == 6) {
            if (wv < 8) {   // x_{32..63} = dA^32 * x_{0..31}
                int t5 = wv >> 1, j5 = wv & 1;
                float4_t aR = {0,0,0,0}, aI = {0,0,0,0};
                cmm_tile<true, false, true>(XRr, XRi, U0f, U1f, t5*16 + fm, j5*16 + fm, fq, aR, aI);
#pragma unroll
                for (int r = 0; r < 4; ++r) {
                    int q = t5*16 + fq*4 + r;
                    U0f[(32 + j5*16 + fm)*SDW + q] = aR[r];
                    U1f[(32 + j5*16 + fm)*SDW + q] = aI[r];
                }
            }
        } else {   // it == 7: g_1[n] = sum_k W[k][n] c[k], W = dA^64 (X^T rows)
            int n = t >> 4, part = t & 15;
            float ar = 0.f, ai = 0.f;
#pragma unroll
            for (int qq = 0; qq < 4; ++qq) {
                int k = part + 16*qq;
                float wr = unpack2(XTr[n*SDW + k]), wi = unpack2(XTi[n*SDW + k]);
                ar += wr*Grf[k] - wi*Gif[k];
                ai += wr*Gif[k] + wi*Grf[k];
            }
#pragma unroll
            for (int off = 8; off; off >>= 1) { ar += __shfl_xor(ar, off); ai += __shfl_xor(ai, off); }
            if (part == 0) { Grf[SDW + n] = ar; Gif[SDW + n] = ai; }
        }
        // squaring (all waves): X <- X*X
        float4_t sR = {0,0,0,0}, sI = {0,0,0,0};
        cmm_tile<true, true, true>(XRr, XRi, XTr, XTi, arow, bcol, fq, sR, sI);
        __syncthreads();
#pragma unroll
        for (int r = 0; r < 4; ++r) {
            int row = ti*16 + fq*4 + r;
            unsigned pr = pack2(sR[r]), pi = pack2(sI[r]);
            XRr[row*SDW + bcol] = pr; XRi[row*SDW + bcol] = pi;
            XTr[bcol*SDW + row] = pr; XTi[bcol*SDW + row] = pi;
        }
        __syncthreads();
    }
    // X = dA^128 ; Xt rows 0..63 = x_0..x_63 ; G rows 0,1 seeded

    // ---- two parallel g-chains: g_{j+2}[n] = sum_k W2[k][n] g_j[k] ----
    {
        int chain = t >> 9;
        int rem = t & 511;
        int n = rem >> 3;
        int part = rem & 7;
#pragma unroll 1
        for (int m = 0; m < 15; ++m) {
            int j = 2*m + chain;
            float ar = 0.f, ai = 0.f;
#pragma unroll
            for (int qq = 0; qq < 8; ++qq) {
                int k = part + 8*qq;
                float wr = unpack2(XTr[n*SDW + k]), wi = unpack2(XTi[n*SDW + k]);
                float gr = Grf[j*SDW + k], gi = Gif[j*SDW + k];
                ar += wr*gr - wi*gi;
                ai += wr*gi + wi*gr;
            }
#pragma unroll
            for (int off = 4; off; off >>= 1) { ar += __shfl_xor(ar, off); ai += __shfl_xor(ai, off); }
            if (part == 0) { Grf[(j+2)*SDW + n] = ar; Gif[(j+2)*SDW + n] = ai; }
            __syncthreads();
        }
    }

    // ---- output K[j][i] = Re(g_j . x_i) via MFMA -> LDS stage ----
    if (wv < 8) {
        int to = wv >> 2, jo = wv & 3;   // 2x4 tiles over 32x64
        float4_t aR = {0,0,0,0}, dummy = {0,0,0,0};
        cmm_tile<false, false, false>(Grf, Gif, U0f, U1f, to*16 + fm, jo*16 + fm, fq, aR, dummy);
#pragma unroll
        for (int r = 0; r < 4; ++r) {
            int j = to*16 + fq*4 + r;
            int i = jo*16 + fm;
            Kof[j*65 + i] = aR[r];
        }
    }
    __syncthreads();

    // ---- coalesced store: 2048 floats as 1024 float2 ----
    {
        int row = t >> 5, col = (t & 31) * 2;
        float2 v = { Kof[row*65 + col], Kof[row*65 + col + 1] };
        ((float2*)(outp + (size_t)h * LSEQ))[t] = v;
    }
}

extern "C" void kernel_launch(void* const* d_in, const int* in_sizes, int n_in,
                              void* d_out, int out_size, void* d_ws, size_t ws_size,
                              hipStream_t stream) {
    const float* A  = (const float*)d_in[0];
    const float* B  = (const float*)d_in[1];
    const float* C  = (const float*)d_in[2];
    const float* ld = (const float*)d_in[3];
    float* out = (float*)d_out;
    ssm_kernel<<<dim3(NH), dim3(NTH), 0, stream>>>(A, B, C, ld, out);
}

// Round 7
// 102.094 us; speedup vs baseline: 3.0257x; 1.1515x over previous
//
#include <hip/hip_runtime.h>
#include <math.h>

// Problem constants (fixed by reference: H=256, N=64, CH=1, L=2048)
#define NH   256
#define NN   64
#define LSEQ 2048
#define SDW  68      // dword row stride: 68 mod 32 = 4 -> b128 16-lane phases tile 32 banks x2
#define NTH  1024

typedef __attribute__((ext_vector_type(8))) short short8;     // 8 bf16 (MFMA A/B frag)
typedef __attribute__((ext_vector_type(4))) float float4_t;   // MFMA C/D frag

#define MFMA(a,b,c) __builtin_amdgcn_mfma_f32_16x16x32_bf16((a),(b),(c),0,0,0)
#define PERM_HI 0x07060302u   // [a.hi16 | b.hi16]
#define PERM_LO 0x05040100u   // [a.lo16 | b.lo16]

// packed element: dword = [bf16hi | bf16lo], value = hi + lo (16-bit mantissa)
static __device__ __forceinline__ unsigned pack2(float v) {
    unsigned hv = __float_as_uint(v) & 0xffff0000u;
    float lo = v - __uint_as_float(hv);
    return __builtin_amdgcn_perm(hv, __float_as_uint(lo), PERM_HI);
}
static __device__ __forceinline__ float unpack2(unsigned w) {
    return __uint_as_float(w & 0xffff0000u) + __uint_as_float(w << 16);
}

// hi/lo frags from 8 fp32 bit-patterns in registers
static __device__ __forceinline__ void frag_vals(const unsigned* e, short8& hi, short8& lo) {
    unsigned lb[8];
#pragma unroll
    for (int m = 0; m < 8; ++m) {
        unsigned hv = e[m] & 0xffff0000u;
        lb[m] = __float_as_uint(__uint_as_float(e[m]) - __uint_as_float(hv));
    }
    union { short8 s; unsigned u[4]; } H, L;
#pragma unroll
    for (int m = 0; m < 4; ++m) {
        H.u[m] = __builtin_amdgcn_perm(e[2*m+1],  e[2*m],  PERM_HI);
        L.u[m] = __builtin_amdgcn_perm(lb[2*m+1], lb[2*m], PERM_HI);
    }
    hi = H.s; lo = L.s;
}
static __device__ __forceinline__ void frag_f32(const float* p, short8& hi, short8& lo) {
    const uint4* q = (const uint4*)p;
    uint4 d0 = q[0], d1 = q[1];
    unsigned e[8] = {d0.x, d0.y, d0.z, d0.w, d1.x, d1.y, d1.z, d1.w};
    frag_vals(e, hi, lo);
}
static __device__ __forceinline__ void frag_packed(const unsigned* p, short8& hi, short8& lo) {
    const uint4* q = (const uint4*)p;
    uint4 d0 = q[0], d1 = q[1];
    unsigned e[8] = {d0.x, d0.y, d0.z, d0.w, d1.x, d1.y, d1.z, d1.w};
    union { short8 s; unsigned u[4]; } H, L;
#pragma unroll
    for (int m = 0; m < 4; ++m) {
        H.u[m] = __builtin_amdgcn_perm(e[2*m+1], e[2*m], PERM_HI);
        L.u[m] = __builtin_amdgcn_perm(e[2*m+1], e[2*m], PERM_LO);
    }
    hi = H.s; lo = L.s;
}
static __device__ __forceinline__ short8 neg8(short8 v) {
    union { short8 s; int i[4]; } u; u.s = v;
#pragma unroll
    for (int m = 0; m < 4; ++m) u.i[m] ^= 0x80008000;
    return u.s;
}

// One 16x16 tile of complex P = A*B, K=64. A read as rows [arow*SDW+k..];
// B read as rows of the B-TRANSPOSE array [bcol*SDW+k..] (both b128-clean).
template<bool AP, bool BP, bool IMAG>
static __device__ __forceinline__ void cmm_tile(
    const void* Ar_, const void* Ai_, const void* Br_, const void* Bi_,
    int arow, int bcol, int fq, float4_t& accR, float4_t& accI)
{
#pragma unroll
    for (int ks = 0; ks < 2; ++ks) {
        const int k0 = ks*32 + fq*8;
        short8 Arh, Arl, Aih, Ail, Brh, Brl, Bih, Bil;
        if (AP) {
            frag_packed((const unsigned*)Ar_ + arow*SDW + k0, Arh, Arl);
            frag_packed((const unsigned*)Ai_ + arow*SDW + k0, Aih, Ail);
        } else {
            frag_f32((const float*)Ar_ + arow*SDW + k0, Arh, Arl);
            frag_f32((const float*)Ai_ + arow*SDW + k0, Aih, Ail);
        }
        if (BP) {
            frag_packed((const unsigned*)Br_ + bcol*SDW + k0, Brh, Brl);
            frag_packed((const unsigned*)Bi_ + bcol*SDW + k0, Bih, Bil);
        } else {
            frag_f32((const float*)Br_ + bcol*SDW + k0, Brh, Brl);
            frag_f32((const float*)Bi_ + bcol*SDW + k0, Bih, Bil);
        }
        short8 nAih = neg8(Aih), nAil = neg8(Ail);
        accR = MFMA(Arh, Brh, accR); accR = MFMA(Arh, Brl, accR); accR = MFMA(Arl, Brh, accR);
        accR = MFMA(nAih, Bih, accR); accR = MFMA(nAih, Bil, accR); accR = MFMA(nAil, Bih, accR);
        if (IMAG) {
            accI = MFMA(Arh, Bih, accI); accI = MFMA(Arh, Bil, accI); accI = MFMA(Arl, Bih, accI);
            accI = MFMA(Aih, Brh, accI); accI = MFMA(Aih, Brl, accI); accI = MFMA(Ail, Brh, accI);
        }
    }
}

// k[h, 64j+i] = Re( g_j . x_i ),  g_j = (dA^64)^T^j c,  x_i = dA^i dB
// All doubling on MFMA:
//   X rows: x_{C+r} = x_r . (dA^C)^T  (B-transpose array = P row-major), C=1..32
//   G rows: g_{C+r} = g_r . dA^{64C}  (B-transpose array = P^T),        C=1..16
// 10-squaring ladder P = dA^2 .. dA^1024 feeds both.
__global__ __launch_bounds__(NTH, 4) void ssm_kernel(
    const float* __restrict__ Ag,
    const float* __restrict__ Bg,
    const float* __restrict__ Cg,
    const float* __restrict__ LogDt,
    float* __restrict__ outp)
{
    __shared__ __align__(16) unsigned char lds[130688];
    unsigned* XRr = (unsigned*)(lds +      0);   // packed P row-major (re)
    unsigned* XRi = (unsigned*)(lds +  17408);   // packed P row-major (im)
    unsigned* XTr = (unsigned*)(lds +  34816);   // packed P^T (re)
    unsigned* XTi = (unsigned*)(lds +  52224);   // packed P^T (im)
    float*    Xfr = (float*)(lds +  69632);      // fp32 Xf[v][q] = x_v[q] ; aliases Newton T^T
    float*    Xfi = (float*)(lds +  87040);
    unsigned* U0u = (unsigned*)Xfr;              // Newton T^T packed (dead before Xf live)
    unsigned* U1u = (unsigned*)Xfi;
    float*    Grf = (float*)(lds + 104448);      // fp32 G[j][q] = g_j[q], 32 rows
    float*    Gif = (float*)(lds + 113152);
    float*    Kof = (float*)(lds + 121856);      // output stage 32 x 65
    float*    bvr = (float*)(lds + 130176);
    float*    bvi = (float*)(lds + 130432);

    const int t    = threadIdx.x;
    const int lane = t & 63;
    const int wv   = t >> 6;                 // 0..15
    const int ti   = wv >> 2, tj = wv & 3;
    const int fm   = lane & 15, fq = lane >> 4;
    const int h    = blockIdx.x;

    const float dt  = expf(LogDt[h]);
    const float hdt = 0.5f * dt;

    const float2* A2 = (const float2*)(Ag + (size_t)h * NN * NN * 2);

    // ---- seed X1 = I + (dt/2)A packed (both orientations); load b, c ----
#pragma unroll
    for (int e = 0; e < 4; ++e) {
        int idx = t + e*NTH;
        int i = idx >> 6, j = idx & 63;
        float2 a = A2[idx];
        unsigned pr = pack2((i == j ? 1.0f : 0.0f) + hdt * a.x);
        unsigned pi = pack2(hdt * a.y);
        XRr[i*SDW + j] = pr; XRi[i*SDW + j] = pi;
        XTr[j*SDW + i] = pr; XTi[j*SDW + i] = pi;
    }
    if (t < NN) {
        float2 bv = ((const float2*)Bg)[h*NN + t];
        float2 cv = ((const float2*)Cg)[h*NN + t];
        bvr[t] = bv.x; bvi[t] = bv.y;
        Grf[t] = cv.x; Gif[t] = cv.y;   // g_0 = c
    }
    __syncthreads();

    const int arow = ti*16 + fm;
    const int bcol = tj*16 + fm;

    // ---- 2 Newton steps: T = 2I - Ab*X (Ab from global); X <- X*T ----
#pragma unroll 1
    for (int step = 0; step < 2; ++step) {
        float4_t aR = {0,0,0,0}, aI = {0,0,0,0};
#pragma unroll
        for (int ks = 0; ks < 2; ++ks) {
            const int k0 = ks*32 + fq*8;
            unsigned vr[8], vi[8];
#pragma unroll
            for (int j = 0; j < 8; ++j) {
                float2 a = A2[arow*NN + k0 + j];
                vr[j] = __float_as_uint((arow == k0 + j ? 1.0f : 0.0f) - hdt * a.x);
                vi[j] = __float_as_uint(-hdt * a.y);
            }
            short8 Arh, Arl, Aih, Ail, Brh, Brl, Bih, Bil;
            frag_vals(vr, Arh, Arl);
            frag_vals(vi, Aih, Ail);
            frag_packed(XTr + bcol*SDW + k0, Brh, Brl);
            frag_packed(XTi + bcol*SDW + k0, Bih, Bil);
            short8 nAih = neg8(Aih), nAil = neg8(Ail);
            aR = MFMA(Arh, Brh, aR); aR = MFMA(Arh, Brl, aR); aR = MFMA(Arl, Brh, aR);
            aR = MFMA(nAih, Bih, aR); aR = MFMA(nAih, Bil, aR); aR = MFMA(nAil, Bih, aR);
            aI = MFMA(Arh, Bih, aI); aI = MFMA(Arh, Bil, aI); aI = MFMA(Arl, Bih, aI);
            aI = MFMA(Aih, Brh, aI); aI = MFMA(Aih, Brl, aI); aI = MFMA(Ail, Brh, aI);
        }
#pragma unroll
        for (int r = 0; r < 4; ++r) {   // write T^T packed into U (dead region)
            int row = ti*16 + fq*4 + r;
            U0u[bcol*SDW + row] = pack2((row == bcol ? 2.0f : 0.0f) - aR[r]);
            U1u[bcol*SDW + row] = pack2(-aI[r]);
        }
        __syncthreads();
        float4_t bR = {0,0,0,0}, bI = {0,0,0,0};
        cmm_tile<true, true, true>(XRr, XRi, U0u, U1u, arow, bcol, fq, bR, bI);
        __syncthreads();   // all reads of X done before overwrite
#pragma unroll
        for (int r = 0; r < 4; ++r) {
            int row = ti*16 + fq*4 + r;
            unsigned pr = pack2(bR[r]), pi = pack2(bI[r]);
            XRr[row*SDW + bcol] = pr; XRi[row*SDW + bcol] = pi;
            XTr[bcol*SDW + row] = pr; XTi[bcol*SDW + row] = pi;
        }
        __syncthreads();
    }
    // P = Minv

    // ---- x_0 = dB = dt * Minv * b -> Xf row 0 ----
    {
        int n = t >> 4, part = t & 15;
        float ar = 0.f, ai = 0.f;
#pragma unroll
        for (int qq = 0; qq < 4; ++qq) {
            int k = part + 16*qq;
            float mr = unpack2(XRr[n*SDW + k]), mi = unpack2(XRi[n*SDW + k]);
            ar += mr*bvr[k] - mi*bvi[k];
            ai += mr*bvi[k] + mi*bvr[k];
        }
#pragma unroll
        for (int off = 8; off; off >>= 1) { ar += __shfl_xor(ar, off); ai += __shfl_xor(ai, off); }
        if (part == 0) { Xfr[n] = dt*ar; Xfi[n] = dt*ai; }
    }
    __syncthreads();   // protect P reads before transform overwrite

    // ---- P = dA = 2*Minv - I (in place, packed, both orientations) ----
#pragma unroll
    for (int e = 0; e < 4; ++e) {
        int idx = t + e*NTH;
        int i = idx >> 6, j = idx & 63;
        float vr = 2.0f*unpack2(XRr[i*SDW + j]) - (i == j ? 1.0f : 0.0f);
        float vi = 2.0f*unpack2(XRi[i*SDW + j]);
        unsigned pr = pack2(vr), pi = pack2(vi);
        XRr[i*SDW + j] = pr; XRi[i*SDW + j] = pi;
        XTr[j*SDW + i] = pr; XTi[j*SDW + i] = pi;
    }
    __syncthreads();

    // ---- s = 1..11: doubling pre-work (uses P = dA^(2^(s-1))) + squaring ----
    // s<=6:  X-round C=2^(s-1): Xf[C+r] = Xf[r] . P^T  -> Bt array = XR (row-major)
    // s>=7:  G-round C=2^(s-7): Gf[C+r] = Gf[r] . P    -> Bt array = XT
    // rows >= C in A are garbage; they only produce garbage rows >= 2C,
    // overwritten by later rounds before use (inductively valid).
#pragma unroll 1
    for (int s = 1; s <= 11; ++s) {
        if (s <= 6) {
            const int C = 1 << (s-1);
            const int nT = (s == 6) ? 8 : 4;
            if (wv < nT) {
                const int rt = wv >> 2, ct = wv & 3;
                float4_t aR = {0,0,0,0}, aI = {0,0,0,0};
                cmm_tile<false, true, true>(Xfr, Xfi, XRr, XRi, rt*16 + fm, ct*16 + fm, fq, aR, aI);
#pragma unroll
                for (int r = 0; r < 4; ++r) {
                    int row = rt*16 + fq*4 + r;
                    Xfr[(C+row)*SDW + ct*16 + fm] = aR[r];
                    Xfi[(C+row)*SDW + ct*16 + fm] = aI[r];
                }
            }
        } else {
            const int C = 1 << (s-7);
            if (wv < 4) {
                float4_t aR = {0,0,0,0}, aI = {0,0,0,0};
                cmm_tile<false, true, true>(Grf, Gif, XTr, XTi, fm, wv*16 + fm, fq, aR, aI);
#pragma unroll
                for (int r = 0; r < 4; ++r) {
                    int row = fq*4 + r;
                    Grf[(C+row)*SDW + wv*16 + fm] = aR[r];
                    Gif[(C+row)*SDW + wv*16 + fm] = aI[r];
                }
            } else if (s == 11 && wv < 8) {
                // overlap: output tiles j=0..15 (Gf rows 0..15 stable; s=11 writes 16..31)
                int jo = wv - 4;
                float4_t aR = {0,0,0,0}, dummy = {0,0,0,0};
                cmm_tile<false, false, false>(Grf, Gif, Xfr, Xfi, fm, jo*16 + fm, fq, aR, dummy);
#pragma unroll
                for (int r = 0; r < 4; ++r)
                    Kof[(fq*4 + r)*65 + jo*16 + fm] = aR[r];
            }
        }
        if (s <= 10) {   // squaring: P <- P*P (all 16 waves)
            float4_t sR = {0,0,0,0}, sI = {0,0,0,0};
            cmm_tile<true, true, true>(XRr, XRi, XTr, XTi, arow, bcol, fq, sR, sI);
            __syncthreads();
#pragma unroll
            for (int r = 0; r < 4; ++r) {
                int row = ti*16 + fq*4 + r;
                unsigned pr = pack2(sR[r]), pi = pack2(sI[r]);
                XRr[row*SDW + bcol] = pr; XRi[row*SDW + bcol] = pi;
                XTr[bcol*SDW + row] = pr; XTi[bcol*SDW + row] = pi;
            }
            __syncthreads();
        } else {
            __syncthreads();
        }
    }
    // Xf rows 0..63 = x_i ; Gf rows 0..31 = g_j ; Kof rows 0..15 done

    // ---- remaining output tiles j=16..31 ----
    if (wv < 4) {
        float4_t aR = {0,0,0,0}, dummy = {0,0,0,0};
        cmm_tile<false, false, false>(Grf, Gif, Xfr, Xfi, 16 + fm, wv*16 + fm, fq, aR, dummy);
#pragma unroll
        for (int r = 0; r < 4; ++r)
            Kof[(16 + fq*4 + r)*65 + wv*16 + fm] = aR[r];
    }
    __syncthreads();

    // ---- coalesced store: 2048 floats as 1024 float2 ----
    {
        int row = t >> 5, col = (t & 31) * 2;
        float2 v = { Kof[row*65 + col], Kof[row*65 + col + 1] };
        ((float2*)(outp + (size_t)h * LSEQ))[t] = v;
    }
}

extern "C" void kernel_launch(void* const* d_in, const int* in_sizes, int n_in,
                              void* d_out, int out_size, void* d_ws, size_t ws_size,
                              hipStream_t stream) {
    const float* A  = (const float*)d_in[0];
    const float* B  = (const float*)d_in[1];
    const float* C  = (const float*)d_in[2];
    const float* ld = (const float*)d_in[3];
    float* out = (float*)d_out;
    ssm_kernel<<<dim3(NH), dim3(NTH), 0, stream>>>(A, B, C, ld, out);
}